// Round 2
// baseline (261.333 us; speedup 1.0000x reference)
//
#include <hip/hip_runtime.h>
#include <hip/hip_fp16.h>

#define DIM 128
#define EPS 1e-5f
#define WPB 4            // waves per block
#define EPT 16           // edges per trip (4 per quarter-wave)

// native clang ext-vectors (needed for __builtin_nontemporal_store)
typedef float vfloat2 __attribute__((ext_vector_type(2)));

// ---------------------------------------------------------------------------
// Prep kernel (fused): convert x fp32 -> fp16; build CSR row_ptr from the
// sorted edge_row (thread e covers rows (row[e-1], row[e]]).
// ---------------------------------------------------------------------------
__global__ void prep_kernel(const float4* __restrict__ x4,
                            __half2* __restrict__ xh2,
                            const int* __restrict__ edge_row,
                            int* __restrict__ row_ptr,
                            int n4, int n_nodes, int n_edges)
{
    int i = blockIdx.x * blockDim.x + threadIdx.x;
    if (i < n4) {
        float4 v = x4[i];
        xh2[2 * i]     = __float22half2_rn(make_float2(v.x, v.y));
        xh2[2 * i + 1] = __float22half2_rn(make_float2(v.z, v.w));
    }
    if (i < n_edges) {
        int cur  = edge_row[i];
        int prev = (i == 0) ? -1 : edge_row[i - 1];
        for (int r = prev + 1; r <= cur; ++r) row_ptr[r] = i;
        if (i == n_edges - 1) {
            for (int r = cur + 1; r <= n_nodes; ++r) row_ptr[r] = n_edges;
        }
    }
}

// ---------------------------------------------------------------------------
// Helpers for the software-pipelined edge loop.
// Masked edges: c -> 0 (hot row 0, stays cache-resident; avoids wasted far
// gathers — R1 showed unmasked c costs +54MB FETCH), w -> 0.
// ---------------------------------------------------------------------------
__device__ __forceinline__
void mask_edges(int4 rc, float4 rw, int off, unsigned len,
                int c[4], float w[4])
{
    const int   cc[4] = {rc.x, rc.y, rc.z, rc.w};
    const float ww[4] = {rw.x, rw.y, rw.z, rw.w};
#pragma unroll
    for (int u = 0; u < 4; ++u) {
        const bool in = (unsigned)(off + u) < len;
        c[u] = in ? cc[u] : 0;
        w[u] = in ? ww[u] : 0.f;
    }
}

__device__ __forceinline__
void issue_gathers(const uint4* __restrict__ xh16, const int c[4], int sub,
                   uint4 v[4])
{
#pragma unroll
    for (int u = 0; u < 4; ++u)
        v[u] = xh16[c[u] * (DIM / 8) + sub];     // 16B/lane; 1024B/instr
}

__device__ __forceinline__
void do_fma(const uint4 v[4], const float w[4], float acc[8])
{
#pragma unroll
    for (int u = 0; u < 4; ++u) {
        const __half* hp = (const __half*)&v[u];
#pragma unroll
        for (int j = 0; j < 8; ++j)              // fp16 operand -> v_fma_mix
            acc[j] = fmaf(w[u], __half2float(hp[j]), acc[j]);
    }
}

// ---------------------------------------------------------------------------
// Main kernel: one wave per node (R0 geometry), software-pipelined 1 trip
// ahead. Issue order is chosen for in-order vmcnt retirement:
//   steady state: wait edge[t+1] = vmcnt(4)  (gathers[t] stay in flight)
//                 issue edge[t+2], issue gathers[t+1]
//                 wait gathers[t] = vmcnt(6), FMA trip t
// One full vmcnt drain per NODE (prologue), not per trip.
// ---------------------------------------------------------------------------
__global__ __launch_bounds__(WPB * 64)
void gnn_fused_kernel(const uint4* __restrict__ xh16,   // fp16 x, 16B units
                      const int*   __restrict__ row_ptr,
                      const int*   __restrict__ edge_col,
                      const float* __restrict__ edge_val,
                      const float* __restrict__ gamma,
                      const float* __restrict__ beta,
                      float*       __restrict__ out,
                      int n_nodes, int n_edges)
{
    const int wave = threadIdx.x >> 6;
    const int lane = threadIdx.x & 63;
    const int q    = lane >> 4;                  // quarter: 4 edges/trip
    const int sub  = lane & 15;                  // dim group [sub*8, sub*8+8)
    const int node = blockIdx.x * WPB + wave;
    if (node >= n_nodes) return;

    const int start = row_ptr[node];
    const int end   = row_ptr[node + 1];
    const unsigned len = (unsigned)(end - start);

    // residual row: issue early, latency hides under the edge loop
    const uint4 xv = xh16[node * (DIM / 8) + sub];

    float acc[8];
#pragma unroll
    for (int k = 0; k < 8; ++k) acc[k] = 0.f;

    const int ebase = start & ~3;                // 16B-align edge vec loads
    const int T     = (end > ebase) ? ((end - ebase + 15) >> 4) : 0;
    const int emax  = n_edges - 4;

    if (T > 0) {
        int c[4];
        float wA[4], wB[4];
        uint4 vA[4], vB[4];

        // ---- prologue: trip 0 ----
        int bA = ebase + 4 * q;                  // this quarter's base, trip 0
        {
            const int bc = min(bA, emax);
            int4   rc = *(const int4*)  (edge_col + bc);
            float4 rw = *(const float4*)(edge_val + bc);
            mask_edges(rc, rw, bA - start, len, c, wA);
        }
        // issue edge[1] BEFORE gathers[0] (in-order vmcnt discipline)
        int bB = bA + EPT;
        int4   rcB = *(const int4*)  (edge_col + min(bB, emax));
        float4 rwB = *(const float4*)(edge_val + min(bB, emax));
        issue_gathers(xh16, c, sub, vA);

        int4 rcA; float4 rwA;
        int t = 0;
        for (;;) {
            // ---- even phase: consume trip t (in vA), prefetch t+1 ----
            if (t + 1 >= T) { do_fma(vA, wA, acc); break; }
            mask_edges(rcB, rwB, bB - start, len, c, wB);   // vmcnt(4)
            const int b2 = bB + EPT;                        // trip t+2 base
            rcA = *(const int4*)  (edge_col + min(b2, emax));
            rwA = *(const float4*)(edge_val + min(b2, emax));
            issue_gathers(xh16, c, sub, vB);
            do_fma(vA, wA, acc);                            // vmcnt(6)

            // ---- odd phase: consume trip t+1 (in vB), prefetch t+2 ----
            if (t + 2 >= T) { do_fma(vB, wB, acc); break; }
            mask_edges(rcA, rwA, b2 - start, len, c, wA);   // vmcnt(4)
            const int b3 = b2 + EPT;                        // trip t+3 base
            rcB = *(const int4*)  (edge_col + min(b3, emax));
            rwB = *(const float4*)(edge_val + min(b3, emax));
            issue_gathers(xh16, c, sub, vA);
            do_fma(vB, wB, acc);                            // vmcnt(6)

            t += 2;
            bB = b3;
        }
    }

    // fold the 4 quarter-waves (disjoint edge subsets) into every lane
#pragma unroll
    for (int k = 0; k < 8; ++k) {
        acc[k] += __shfl_xor(acc[k], 16, 64);
        acc[k] += __shfl_xor(acc[k], 32, 64);
    }

    // residual from fp16 x
    const __half* xp = (const __half*)&xv;
    float h[8];
#pragma unroll
    for (int j = 0; j < 8; ++j) h[j] = acc[j] + __half2float(xp[j]);

    // layernorm stats: per-lane over 8 dims, then butterfly over sub (1,2,4,8)
    float s = 0.f, sq = 0.f;
#pragma unroll
    for (int k = 0; k < 8; ++k) { s += h[k]; sq += h[k] * h[k]; }
#pragma unroll
    for (int off = 1; off <= 8; off <<= 1) {
        s  += __shfl_xor(s,  off, 64);
        sq += __shfl_xor(sq, off, 64);
    }
    const float mean = s * (1.0f / (float)DIM);
    const float var  = sq * (1.0f / (float)DIM) - mean * mean;
    const float rs   = rsqrtf(var + EPS);

    // lane (q,sub) writes dims sub*8 + 2q + {0,1} (512B contiguous per node)
    float hx = (q < 2) ? ((q == 0) ? h[0] : h[2]) : ((q == 2) ? h[4] : h[6]);
    float hy = (q < 2) ? ((q == 0) ? h[1] : h[3]) : ((q == 2) ? h[5] : h[7]);
    const int didx = sub * 4 + q;
    const float2 g = ((const float2*)gamma)[didx];
    const float2 b = ((const float2*)beta)[didx];
    vfloat2 o;
    o.x = (hx - mean) * rs * g.x + b.x;
    o.y = (hy - mean) * rs * g.y + b.y;
    __builtin_nontemporal_store(o, (vfloat2*)out + node * (DIM / 2) + didx);
}

extern "C" void kernel_launch(void* const* d_in, const int* in_sizes, int n_in,
                              void* d_out, int out_size, void* d_ws, size_t ws_size,
                              hipStream_t stream)
{
    const float* x        = (const float*)d_in[0];
    const int*   edge_row = (const int*)  d_in[1];
    const int*   edge_col = (const int*)  d_in[2];
    const float* edge_val = (const float*)d_in[3];
    const float* gamma    = (const float*)d_in[4];
    const float* beta     = (const float*)d_in[5];
    float*       out      = (float*)d_out;

    const int n_nodes = in_sizes[0] / DIM;   // 100000
    const int n_edges = in_sizes[1];         // 3200000
    const int n_elem  = in_sizes[0];         // N*DIM
    const int n4      = n_elem / 4;

    // workspace: [x_half: n_elem*2 B][row_ptr: (n_nodes+1)*4 B]
    __half2* xh2     = (__half2*)d_ws;
    int*     row_ptr = (int*)((char*)d_ws + (size_t)n_elem * sizeof(__half));

    int prep_threads = (n4 > n_edges) ? n4 : n_edges;
    prep_kernel<<<(prep_threads + 255) / 256, 256, 0, stream>>>(
        (const float4*)x, xh2, edge_row, row_ptr, n4, n_nodes, n_edges);

    const int blocks = (n_nodes + WPB - 1) / WPB;
    gnn_fused_kernel<<<blocks, WPB * 64, 0, stream>>>(
        (const uint4*)d_ws, row_ptr, edge_col, edge_val, gamma, beta, out,
        n_nodes, n_edges);
}